// Round 7
// baseline (267.063 us; speedup 1.0000x reference)
//
#include <hip/hip_runtime.h>

#define S_LEN 512
#define B_DIM 1024
#define T_DIM 48
#define L2E 1.4426950408889634f
#define LN2 0.6931471805599453f

// v_exp_f32 computes 2^x ; v_log_f32 computes log2(x)
#define EXP2F(x) __builtin_amdgcn_exp2f(x)
#define LOG2F(x) __builtin_amdgcn_logf(x)

// ---- DPP wave-64 reduction helpers (full result valid in lane 63) ----
template <int CTRL, int RMASK>
__device__ __forceinline__ float dppmovf(float v) {
  return __int_as_float(__builtin_amdgcn_update_dpp(
      __float_as_int(v), __float_as_int(v), CTRL, RMASK, 0xF, false));
}
template <int CTRL, int RMASK>
__device__ __forceinline__ float dppmaxf(float m) {
  return fmaxf(m, dppmovf<CTRL, RMASK>(m));
}
template <int CTRL, int RMASK>
__device__ __forceinline__ float dppaddf(float m) {
  return m + dppmovf<CTRL, RMASK>(m);
}

__device__ __forceinline__ float wave_max63(float m) {
  m = dppmaxf<0xB1, 0xF>(m);   // xor 1
  m = dppmaxf<0x4E, 0xF>(m);   // xor 2
  m = dppmaxf<0x141, 0xF>(m);  // xor 4 (row_half_mirror)
  m = dppmaxf<0x140, 0xF>(m);  // xor 8 (row_mirror)
  m = dppmaxf<0x142, 0xA>(m);  // row_bcast15 -> rows 1,3
  m = dppmaxf<0x143, 0xC>(m);  // row_bcast31 -> rows 2,3 ; lane63 = full max
  return __int_as_float(__builtin_amdgcn_readlane(__float_as_int(m), 63));
}
__device__ __forceinline__ float wave_sum63(float m) {
  m = dppaddf<0xB1, 0xF>(m);
  m = dppaddf<0x4E, 0xF>(m);
  m = dppaddf<0x141, 0xF>(m);
  m = dppaddf<0x140, 0xF>(m);
  m = dppaddf<0x142, 0xA>(m);
  m = dppaddf<0x143, 0xC>(m);
  return __int_as_float(__builtin_amdgcn_readlane(__float_as_int(m), 63));
}

// ---- main scan: blocks 0..1023 = forward(LSE) chain, 1024..2047 = viterbi(max).
// One wave per chain; lane = tag index, lanes >= 48 clone lane 47.
// Per-step all-to-all broadcast via double-buffered all-f32 LDS: each lane
// posts its float, __syncthreads(), then all lanes read the 48-float vector
// as 12x float4 same-address broadcasts (conflict-free). All hot-loop math
// is plain f32 (v_fma_f32 / v_max_f32 / v_exp_f32 / v_log_f32) -- no packed
// f16, no hand-written VOP3P asm.
__global__ __launch_bounds__(64)
void crf_scan(const float* __restrict__ em, const float* __restrict__ mask,
              const float* __restrict__ trans, const float* __restrict__ startT,
              const float* __restrict__ stopT, float* __restrict__ out)
{
  __shared__ __align__(16) float Pbuf[2][64];

  const int b    = blockIdx.x & (B_DIM - 1);
  const int mode = blockIdx.x >> 10;   // 0 = fv, 1 = vv
  const int i    = threadIdx.x;
  const int ri   = (i < T_DIM) ? i : (T_DIM - 1);

  // absolute-coordinate state (f32 range is ample: |v| <= ~4000)
  float v = startT[ri] + em[(size_t)b * T_DIM + ri];

  const float* emb = em + (size_t)b * T_DIM + ri;
  const size_t estep = (size_t)B_DIM * T_DIM;
  float e1 = emb[1 * estep];
  float e2 = emb[2 * estep];
  float e3 = emb[3 * estep];
  float mk = mask[B_DIM + b];

  if (mode == 0) {
    // per-lane row ri of exp(trans) in f32 registers
    float Ef[T_DIM];
#pragma unroll
    for (int k = 0; k < T_DIM; ++k)
      Ef[k] = EXP2F(trans[ri * T_DIM + k] * L2E);

    for (int s = 1; s < S_LEN; ++s) {
      int sp = (s + 3 < S_LEN) ? s + 3 : S_LEN - 1;
      float ep  = emb[(size_t)sp * estep];
      int sn = (s + 1 < S_LEN) ? s + 1 : S_LEN - 1;
      float mkn = mask[sn * B_DIM + b];

      float mf = wave_max63(v);                      // for exp stability only
      float p  = EXP2F((v - mf) * L2E);              // in [0,1]
      Pbuf[s & 1][i] = p;
      __syncthreads();
      const float4* lds4 = (const float4*)Pbuf[s & 1];

      float a0 = 0.f, a1 = 0.f, a2 = 0.f, a3 = 0.f;  // 4 independent chains
#pragma unroll
      for (int k = 0; k < 12; ++k) {
        float4 q = lds4[k];                          // broadcast read
        a0 = fmaf(q.x, Ef[4 * k + 0], a0);
        a1 = fmaf(q.y, Ef[4 * k + 1], a1);
        a2 = fmaf(q.z, Ef[4 * k + 2], a2);
        a3 = fmaf(q.w, Ef[4 * k + 3], a3);
      }
      float accF = (a0 + a1) + (a2 + a3);            // sum_j p_j * exp(t_ij)

      // new_fv = em + mf + ln(accF), in absolute coordinates
      float fnew = fmaf(LN2, LOG2F(fmaxf(accF, 1e-30f)), e1 + mf);
      v = fmaf(mk, fnew - v, v);                     // mask blend

      e1 = e2; e2 = e3; e3 = ep; mk = mkn;
    }
    float q  = v + stopT[ri];
    float mq = wave_max63(q);
    float e  = EXP2F((q - mq) * L2E);
    e = (i < T_DIM) ? e : 0.f;                       // zero clone lanes
    float alpha = mq + LN2 * LOG2F(wave_sum63(e));
    if (i == 0) out[1 + B_DIM + b] = alpha;
  } else {
    float Tf[T_DIM];
#pragma unroll
    for (int k = 0; k < T_DIM; ++k)
      Tf[k] = trans[ri * T_DIM + k];

    for (int s = 1; s < S_LEN; ++s) {
      int sp = (s + 3 < S_LEN) ? s + 3 : S_LEN - 1;
      float ep  = emb[(size_t)sp * estep];
      int sn = (s + 1 < S_LEN) ? s + 1 : S_LEN - 1;
      float mkn = mask[sn * B_DIM + b];

      Pbuf[s & 1][i] = v;                            // raw f32 state
      __syncthreads();
      const float4* lds4 = (const float4*)Pbuf[s & 1];

      float m0 = -3.0e38f, m1 = -3.0e38f, m2 = -3.0e38f, m3 = -3.0e38f;
#pragma unroll
      for (int k = 0; k < 12; ++k) {
        float4 q = lds4[k];
        m0 = fmaxf(m0, q.x + Tf[4 * k + 0]);
        m1 = fmaxf(m1, q.y + Tf[4 * k + 1]);
        m2 = fmaxf(m2, q.z + Tf[4 * k + 2]);
        m3 = fmaxf(m3, q.w + Tf[4 * k + 3]);
      }
      float mx = fmaxf(fmaxf(m0, m1), fmaxf(m2, m3));  // max_j (v_j + t_ij)

      float vnew = e1 + mx;
      v = fmaf(mk, vnew - v, v);                     // mask blend

      e1 = e2; e2 = e3; e3 = ep; mk = mkn;
    }
    float best = wave_max63(v + stopT[ri]);
    if (i == 0) out[1 + 2 * B_DIM + b] = best;
  }
}

// ---- real-path score: one block per b, deterministic LDS tree reduction ----
__global__ __launch_bounds__(256)
void crf_real(const float* __restrict__ em, const int* __restrict__ tags,
              const float* __restrict__ mask, const float* __restrict__ trans,
              const float* __restrict__ startT, const float* __restrict__ stopT,
              float* __restrict__ out)
{
  __shared__ float red[256];
  const int b = blockIdx.x;
  const int t = threadIdx.x;
  float acc = 0.f;
  for (int s = 1 + t; s < S_LEN; s += 256) {
    int   tp  = tags[(s - 1) * B_DIM + b];
    int   tc  = tags[s * B_DIM + b];
    float mkv = mask[s * B_DIM + b];
    float emt = em[((size_t)s * B_DIM + b) * T_DIM + tc];
    acc = fmaf(mkv, trans[tp * T_DIM + tc] + emt, acc);
  }
  red[t] = acc;
  __syncthreads();
  for (int w = 128; w > 0; w >>= 1) {
    if (t < w) red[t] += red[t + w];
    __syncthreads();
  }
  if (t == 0)
    out[1 + b] = startT[tags[b]] + stopT[tags[(S_LEN - 1) * B_DIM + b]] + red[0];
}

// ---- loss = mean(alpha - real) ----
__global__ __launch_bounds__(256)
void crf_loss(float* __restrict__ out)
{
  __shared__ float red[256];
  int t = threadIdx.x;
  float a = 0.f;
  for (int b = t; b < B_DIM; b += 256)
    a += out[1 + B_DIM + b] - out[1 + b];
  red[t] = a;
  __syncthreads();
  for (int w = 128; w > 0; w >>= 1) {
    if (t < w) red[t] += red[t + w];
    __syncthreads();
  }
  if (t == 0) out[0] = red[0] * (1.0f / B_DIM);
}

extern "C" void kernel_launch(void* const* d_in, const int* in_sizes, int n_in,
                              void* d_out, int out_size, void* d_ws, size_t ws_size,
                              hipStream_t stream) {
  (void)in_sizes; (void)n_in; (void)d_ws; (void)ws_size; (void)out_size;
  const float* em     = (const float*)d_in[0];
  const int*   tags   = (const int*)d_in[1];
  const float* mask   = (const float*)d_in[2];
  const float* trans  = (const float*)d_in[3];
  const float* startT = (const float*)d_in[4];
  const float* stopT  = (const float*)d_in[5];
  float* out = (float*)d_out;

  hipLaunchKernelGGL(crf_scan, dim3(2 * B_DIM), dim3(64), 0, stream,
                     em, mask, trans, startT, stopT, out);
  hipLaunchKernelGGL(crf_real, dim3(B_DIM), dim3(256), 0, stream,
                     em, tags, mask, trans, startT, stopT, out);
  hipLaunchKernelGGL(crf_loss, dim3(1), dim3(256), 0, stream, out);
}

// Round 9
// 238.586 us; speedup vs baseline: 1.1194x; 1.1194x over previous
//
#include <hip/hip_runtime.h>
#include <hip/hip_fp16.h>

#define S_LEN 512
#define B_DIM 1024
#define T_DIM 48
#define L2E 1.4426950408889634f
#define LN2 0.6931471805599453f

// v_exp_f32 computes 2^x ; v_log_f32 computes log2(x)
#define EXP2F(x) __builtin_amdgcn_exp2f(x)
#define LOG2F(x) __builtin_amdgcn_logf(x)

typedef _Float16 h2v __attribute__((ext_vector_type(2)));

// packed f16 max (ROCm 7.2 lacks __hmax2): <2 x half> llvm.maxnum -> v_pk_max_f16
__device__ __forceinline__ __half2 hmax2(__half2 a, __half2 b) {
  h2v r = __builtin_elementwise_max(__builtin_bit_cast(h2v, a),
                                    __builtin_bit_cast(h2v, b));
  return __builtin_bit_cast(__half2, r);
}

// broadcast the 32-bit __half2 held by `lane` to all lanes (readlane -> SGPR)
__device__ __forceinline__ __half2 bpick(__half2 src, int lane) {
  int s = __builtin_amdgcn_readlane(__builtin_bit_cast(int, src), lane);
  return __builtin_bit_cast(__half2, s);
}

// ---- DPP wave-64 reduction helpers (full result valid in lane 63) ----
template <int CTRL, int RMASK>
__device__ __forceinline__ float dppmovf(float v) {
  return __int_as_float(__builtin_amdgcn_update_dpp(
      __float_as_int(v), __float_as_int(v), CTRL, RMASK, 0xF, false));
}
template <int CTRL, int RMASK>
__device__ __forceinline__ float dppmaxf(float m) {
  return fmaxf(m, dppmovf<CTRL, RMASK>(m));
}
template <int CTRL, int RMASK>
__device__ __forceinline__ float dppaddf(float m) {
  return m + dppmovf<CTRL, RMASK>(m);
}

__device__ __forceinline__ float wave_max63(float m) {
  m = dppmaxf<0xB1, 0xF>(m);   // xor 1
  m = dppmaxf<0x4E, 0xF>(m);   // xor 2
  m = dppmaxf<0x141, 0xF>(m);  // xor 4 (row_half_mirror)
  m = dppmaxf<0x140, 0xF>(m);  // xor 8 (row_mirror)
  m = dppmaxf<0x142, 0xA>(m);  // row_bcast15 -> rows 1,3
  m = dppmaxf<0x143, 0xC>(m);  // row_bcast31 -> rows 2,3 ; lane63 = full max
  return __int_as_float(__builtin_amdgcn_readlane(__float_as_int(m), 63));
}
__device__ __forceinline__ float wave_sum63(float m) {
  m = dppaddf<0xB1, 0xF>(m);
  m = dppaddf<0x4E, 0xF>(m);
  m = dppaddf<0x141, 0xF>(m);
  m = dppaddf<0x140, 0xF>(m);
  m = dppaddf<0x142, 0xA>(m);
  m = dppaddf<0x143, 0xC>(m);
  return __int_as_float(__builtin_amdgcn_readlane(__float_as_int(m), 63));
}

// ---- main scan: blocks 0..1023 = forward(LSE) chain, 1024..2047 = viterbi(max).
// One wave per chain; lane = tag index, lanes >= 48 clone lane 47.
// Broadcast of the 48-state vector: DPP quad-swap packs (x_i, x_{i^1}) into an
// f16 pair per even lane; 24 v_readlane broadcasts feed packed __half2 math
// (__hfma2 / __hadd2 / hmax2 -> v_pk_* VOP3P). No LDS, no barriers.
__global__ __launch_bounds__(64)
void crf_scan(const float* __restrict__ em, const float* __restrict__ mask,
              const float* __restrict__ trans, const float* __restrict__ startT,
              const float* __restrict__ stopT, float* __restrict__ out)
{
  const int b    = blockIdx.x & (B_DIM - 1);
  const int mode = blockIdx.x >> 10;   // 0 = fv, 1 = vv
  const int i    = threadIdx.x;
  const int ri   = (i < T_DIM) ? i : (T_DIM - 1);

  float v = startT[ri] + em[(size_t)b * T_DIM + ri];

  const float* emb = em + (size_t)b * T_DIM + ri;
  const size_t estep = (size_t)B_DIM * T_DIM;
  float e1 = emb[1 * estep];
  float e2 = emb[2 * estep];
  float e3 = emb[3 * estep];
  float mk = mask[B_DIM + b];

  if (mode == 0) {
    // per-lane row ri of exp(trans), f16 RNE packed over j-pairs
    __half2 Epk[24];
#pragma unroll
    for (int k = 0; k < 24; ++k)
      Epk[k] = __floats2half2_rn(EXP2F(trans[ri * T_DIM + 2 * k]     * L2E),
                                 EXP2F(trans[ri * T_DIM + 2 * k + 1] * L2E));

    for (int s = 1; s < S_LEN; ++s) {
      int sp = (s + 3 < S_LEN) ? s + 3 : S_LEN - 1;
      float ep  = emb[(size_t)sp * estep];
      int sn = (s + 1 < S_LEN) ? s + 1 : S_LEN - 1;
      float mkn = mask[sn * B_DIM + b];

      float mf = wave_max63(v);                      // exp stability
      float p  = EXP2F((v - mf) * L2E);              // in [0,1]
      float pn = dppmovf<0xB1, 0xF>(p);              // neighbor (i^1)
      __half2 pp = __floats2half2_rn(p, pn);         // even lane 2k: (p_2k, p_2k+1)

      __half2 a0 = __float2half2_rn(0.f), a1 = a0, a2 = a0, a3 = a0;
#pragma unroll
      for (int k = 0; k < 6; ++k) {
        a0 = __hfma2(bpick(pp, 2 * k),        Epk[k],      a0);
        a1 = __hfma2(bpick(pp, 2 * (k + 6)),  Epk[k + 6],  a1);
        a2 = __hfma2(bpick(pp, 2 * (k + 12)), Epk[k + 12], a2);
        a3 = __hfma2(bpick(pp, 2 * (k + 18)), Epk[k + 18], a3);
      }
      a0 = __hadd2(a0, a1); a2 = __hadd2(a2, a3); a0 = __hadd2(a0, a2);
      float accF = __low2float(a0) + __high2float(a0);  // sum_j p_j*exp(t_ij)

      // new_fv = em + mf + ln(accF), absolute coordinates
      float fnew = fmaf(LN2, LOG2F(fmaxf(accF, 1e-30f)), e1 + mf);
      v = fmaf(mk, fnew - v, v);                     // mask blend

      e1 = e2; e2 = e3; e3 = ep; mk = mkn;
    }
    float q  = v + stopT[ri];
    float mq = wave_max63(q);
    float e  = EXP2F((q - mq) * L2E);
    e = (i < T_DIM) ? e : 0.f;                       // zero clone lanes
    float alpha = mq + LN2 * LOG2F(wave_sum63(e));
    if (i == 0) out[1 + B_DIM + b] = alpha;
  } else {
    __half2 Tpk[24];
#pragma unroll
    for (int k = 0; k < 24; ++k)
      Tpk[k] = __floats2half2_rn(trans[ri * T_DIM + 2 * k],
                                 trans[ri * T_DIM + 2 * k + 1]);

    // rebased state for f16 range: true vv = OFF + v_rebased
    float OFF = 0.f;
    const __half2 NEG = __floats2half2_rn(-60000.f, -60000.f);

    for (int s = 1; s < S_LEN; ++s) {
      int sp = (s + 3 < S_LEN) ? s + 3 : S_LEN - 1;
      float ep  = emb[(size_t)sp * estep];
      int sn = (s + 1 < S_LEN) ? s + 1 : S_LEN - 1;
      float mkn = mask[sn * B_DIM + b];

      float mv = wave_max63(v);
      float vr = v - mv;                             // <= 0, f16-safe
      float vn_ = dppmovf<0xB1, 0xF>(vr);
      __half2 vp = __floats2half2_rn(vr, vn_);       // even lane 2k: (vr_2k, vr_2k+1)

      __half2 m0 = NEG, m1 = NEG;
#pragma unroll
      for (int k = 0; k < 12; ++k) {
        m0 = hmax2(m0, __hadd2(bpick(vp, 2 * k),        Tpk[k]));
        m1 = hmax2(m1, __hadd2(bpick(vp, 2 * (k + 12)), Tpk[k + 12]));
      }
      m0 = hmax2(m0, m1);
      float mx = fmaxf(__low2float(m0), __high2float(m0));  // max_j(vr_j+t_ij)

      float vnew = e1 + mx;                          // rebased coords
      float vold = v - mv;
      v = fmaf(mk, vnew - vold, vold);
      OFF += mv;

      e1 = e2; e2 = e3; e3 = ep; mk = mkn;
    }
    float best = OFF + wave_max63(v + stopT[ri]);
    if (i == 0) out[1 + 2 * B_DIM + b] = best;
  }
}

// ---- real-path score: one block per b, deterministic LDS tree reduction ----
__global__ __launch_bounds__(256)
void crf_real(const float* __restrict__ em, const int* __restrict__ tags,
              const float* __restrict__ mask, const float* __restrict__ trans,
              const float* __restrict__ startT, const float* __restrict__ stopT,
              float* __restrict__ out)
{
  __shared__ float red[256];
  const int b = blockIdx.x;
  const int t = threadIdx.x;
  float acc = 0.f;
  for (int s = 1 + t; s < S_LEN; s += 256) {
    int   tp  = tags[(s - 1) * B_DIM + b];
    int   tc  = tags[s * B_DIM + b];
    float mkv = mask[s * B_DIM + b];
    float emt = em[((size_t)s * B_DIM + b) * T_DIM + tc];
    acc = fmaf(mkv, trans[tp * T_DIM + tc] + emt, acc);
  }
  red[t] = acc;
  __syncthreads();
  for (int w = 128; w > 0; w >>= 1) {
    if (t < w) red[t] += red[t + w];
    __syncthreads();
  }
  if (t == 0)
    out[1 + b] = startT[tags[b]] + stopT[tags[(S_LEN - 1) * B_DIM + b]] + red[0];
}

// ---- loss = mean(alpha - real) ----
__global__ __launch_bounds__(256)
void crf_loss(float* __restrict__ out)
{
  __shared__ float red[256];
  int t = threadIdx.x;
  float a = 0.f;
  for (int b = t; b < B_DIM; b += 256)
    a += out[1 + B_DIM + b] - out[1 + b];
  red[t] = a;
  __syncthreads();
  for (int w = 128; w > 0; w >>= 1) {
    if (t < w) red[t] += red[t + w];
    __syncthreads();
  }
  if (t == 0) out[0] = red[0] * (1.0f / B_DIM);
}

extern "C" void kernel_launch(void* const* d_in, const int* in_sizes, int n_in,
                              void* d_out, int out_size, void* d_ws, size_t ws_size,
                              hipStream_t stream) {
  (void)in_sizes; (void)n_in; (void)d_ws; (void)ws_size; (void)out_size;
  const float* em     = (const float*)d_in[0];
  const int*   tags   = (const int*)d_in[1];
  const float* mask   = (const float*)d_in[2];
  const float* trans  = (const float*)d_in[3];
  const float* startT = (const float*)d_in[4];
  const float* stopT  = (const float*)d_in[5];
  float* out = (float*)d_out;

  hipLaunchKernelGGL(crf_scan, dim3(2 * B_DIM), dim3(64), 0, stream,
                     em, mask, trans, startT, stopT, out);
  hipLaunchKernelGGL(crf_real, dim3(B_DIM), dim3(256), 0, stream,
                     em, tags, mask, trans, startT, stopT, out);
  hipLaunchKernelGGL(crf_loss, dim3(1), dim3(256), 0, stream, out);
}